// Round 1
// baseline (11193.683 us; speedup 1.0000x reference)
//
#include <hip/hip_runtime.h>
#include <hip/hip_bf16.h>
#include <math.h>

// Problem constants
#define Bb 32
#define Dd 512
#define Ss 512      // NC + Hs*Ws
#define NHh 8
#define DHh 64
#define MLPm 2048
#define NCc 256
#define INNERi 512
#define Mrows (Bb*Ss)   // 16384

typedef __bf16 bf16x8 __attribute__((ext_vector_type(8)));
typedef float floatx4 __attribute__((ext_vector_type(4)));

__device__ __forceinline__ void load_lds16(const void* g, void* l) {
  __builtin_amdgcn_global_load_lds(
      (__attribute__((address_space(1))) void*)(g),
      (__attribute__((address_space(3))) void*)(l), 16, 0, 0);
}

// ---------------------------------------------------------------------------
// Tiled transpose + fp32->bf16 downcast: in (K,N) fp32 -> out (N,K) bf16
// grid: (N/32, K/32, DEPTH), block (32,8)
// ---------------------------------------------------------------------------
__global__ void transpose_w(const float* __restrict__ in, __hip_bfloat16* __restrict__ out,
                            int K, int N, size_t in_ls, size_t out_ls)
{
  __shared__ float tile[32][33];
  in  += (size_t)blockIdx.z * in_ls;
  out += (size_t)blockIdx.z * out_ls;
  int n0 = blockIdx.x * 32, k0 = blockIdx.y * 32;
  int tx = threadIdx.x;
  #pragma unroll
  for (int i = threadIdx.y; i < 32; i += 8)
    tile[i][tx] = in[(size_t)(k0 + i) * N + n0 + tx];
  __syncthreads();
  #pragma unroll
  for (int i = threadIdx.y; i < 32; i += 8)
    out[(size_t)(n0 + i) * K + k0 + tx] = __float2bfloat16(tile[tx][i]);
}

// ---------------------------------------------------------------------------
// Prologue: build x[b,s,:] (slots+slot_pos | z^T+pos), then LayerNorm(norm_w/b)
// One wave per row. grid: B*S blocks of 64.
// ---------------------------------------------------------------------------
__global__ void prologue_kernel(const float* __restrict__ z, const float* __restrict__ slots,
                                const float* __restrict__ pos, const float* __restrict__ spos,
                                const float* __restrict__ nw, const float* __restrict__ nb,
                                float* __restrict__ x)
{
  int row = blockIdx.x;            // b*S + s
  int b = row >> 9, s = row & 511;
  int lane = threadIdx.x;
  float v[8];
  float sum = 0.f;
  #pragma unroll
  for (int j = 0; j < 8; ++j) {
    int d = lane + j * 64;
    float t;
    if (s < NCc) t = slots[((size_t)b * NCc + s) * Dd + d] + spos[(size_t)s * Dd + d];
    else {
      int sp = s - NCc;
      t = z[((size_t)b * Dd + d) * 256 + sp] + pos[(size_t)sp * Dd + d];
    }
    v[j] = t; sum += t;
  }
  #pragma unroll
  for (int o = 32; o; o >>= 1) sum += __shfl_xor(sum, o);
  float mean = sum * (1.f / Dd);
  float vs = 0.f;
  #pragma unroll
  for (int j = 0; j < 8; ++j) { float d = v[j] - mean; vs += d * d; }
  #pragma unroll
  for (int o = 32; o; o >>= 1) vs += __shfl_xor(vs, o);
  float rs = rsqrtf(vs * (1.f / Dd) + 1e-5f);
  #pragma unroll
  for (int j = 0; j < 8; ++j) {
    int d = lane + j * 64;
    x[(size_t)row * Dd + d] = (v[j] - mean) * rs * nw[d] + nb[d];
  }
}

// ---------------------------------------------------------------------------
// LayerNorm: x fp32 (rows,512) -> y bf16, per-layer w/b. 4 waves/block, 1 row/wave.
// ---------------------------------------------------------------------------
__global__ void ln_kernel(const float* __restrict__ x, const float* __restrict__ w,
                          const float* __restrict__ b, __hip_bfloat16* __restrict__ y)
{
  int row = blockIdx.x * 4 + (threadIdx.x >> 6);
  int lane = threadIdx.x & 63;
  const float* xr = x + (size_t)row * Dd;
  float v[8];
  float sum = 0.f;
  #pragma unroll
  for (int j = 0; j < 8; ++j) { v[j] = xr[lane + j * 64]; sum += v[j]; }
  #pragma unroll
  for (int o = 32; o; o >>= 1) sum += __shfl_xor(sum, o);
  float mean = sum * (1.f / Dd);
  float vs = 0.f;
  #pragma unroll
  for (int j = 0; j < 8; ++j) { float d = v[j] - mean; vs += d * d; }
  #pragma unroll
  for (int o = 32; o; o >>= 1) vs += __shfl_xor(vs, o);
  float rs = rsqrtf(vs * (1.f / Dd) + 1e-5f);
  #pragma unroll
  for (int j = 0; j < 8; ++j) {
    int d = lane + j * 64;
    y[(size_t)row * Dd + d] = __float2bfloat16((v[j] - mean) * rs * w[d] + b[d]);
  }
}

// ---------------------------------------------------------------------------
// bf16 MFMA GEMM: C(M,N) = A(M,K) @ Bt(N,K)^T  [+bias] [+res] [gelu]
// MODE 0: -> bf16 out (no bias)
// MODE 1: -> f32 out = acc + bias[n] + res[m,n]
// MODE 2: -> bf16 out = gelu(acc + bias[n])
// 128x128 tile, BK=64, 256 threads (4 waves, 2x2 of 64x64), mfma 16x16x32 bf16.
// Verified fragment layouts: A/B lane = (l&15) row, k = (l>>4)*8+j;
// C/D: row = (l>>4)*4 + r, col = l&15.
// ---------------------------------------------------------------------------
template <int MODE>
__global__ __launch_bounds__(256, 2)
void gemm_bt(const __hip_bfloat16* __restrict__ A, const __hip_bfloat16* __restrict__ Bt,
             const float* __restrict__ bias, const float* __restrict__ res,
             void* __restrict__ Out, int M, int N, int K)
{
  constexpr int BM = 128, BN = 128, BK = 64;
  __shared__ __align__(16) __hip_bfloat16 As[BM * BK];
  __shared__ __align__(16) __hip_bfloat16 Bs[BN * BK];
  const int tid = threadIdx.x;
  const int lane = tid & 63;
  const int wave = tid >> 6;
  const int m0 = blockIdx.y * BM;
  const int n0 = blockIdx.x * BN;
  const int wm = (wave & 1) * 64;
  const int wn = (wave >> 1) * 64;
  const int quad = lane >> 4;
  const int lrow = lane & 15;

  floatx4 acc[4][4];
  #pragma unroll
  for (int i = 0; i < 4; ++i)
    #pragma unroll
    for (int j = 0; j < 4; ++j) {
      floatx4 z4 = {0.f, 0.f, 0.f, 0.f};
      acc[i][j] = z4;
    }

  for (int k0 = 0; k0 < K; k0 += BK) {
    // stage A tile (128 x 64 bf16, row-major) via async global->LDS, 16B/lane
    #pragma unroll
    for (int it = 0; it < 4; ++it) {
      int c = it * 256 + tid;
      int row = c >> 3, cc = c & 7;     // 8 chunks of 16B per 64-elem row
      load_lds16(A + (size_t)(m0 + row) * K + k0 + cc * 8, As + c * 8);
    }
    #pragma unroll
    for (int it = 0; it < 4; ++it) {
      int c = it * 256 + tid;
      int row = c >> 3, cc = c & 7;
      load_lds16(Bt + (size_t)(n0 + row) * K + k0 + cc * 8, Bs + c * 8);
    }
    __syncthreads();   // drains vmcnt -> LDS valid

    #pragma unroll
    for (int k1 = 0; k1 < BK; k1 += 32) {
      bf16x8 a[4], b[4];
      #pragma unroll
      for (int i = 0; i < 4; ++i)
        a[i] = *reinterpret_cast<const bf16x8*>(&As[(wm + i * 16 + lrow) * BK + k1 + quad * 8]);
      #pragma unroll
      for (int i = 0; i < 4; ++i)
        b[i] = *reinterpret_cast<const bf16x8*>(&Bs[(wn + i * 16 + lrow) * BK + k1 + quad * 8]);
      #pragma unroll
      for (int mi = 0; mi < 4; ++mi)
        #pragma unroll
        for (int ni = 0; ni < 4; ++ni)
          acc[mi][ni] = __builtin_amdgcn_mfma_f32_16x16x32_bf16(a[mi], b[ni], acc[mi][ni], 0, 0, 0);
    }
    __syncthreads();
  }

  // epilogue
  #pragma unroll
  for (int mi = 0; mi < 4; ++mi) {
    #pragma unroll
    for (int r = 0; r < 4; ++r) {
      int gm = m0 + wm + mi * 16 + quad * 4 + r;
      #pragma unroll
      for (int ni = 0; ni < 4; ++ni) {
        int gn = n0 + wn + ni * 16 + lrow;
        float v = acc[mi][ni][r];
        size_t oi = (size_t)gm * N + gn;
        if (MODE == 0) {
          ((__hip_bfloat16*)Out)[oi] = __float2bfloat16(v);
        } else if (MODE == 1) {
          ((float*)Out)[oi] = v + bias[gn] + res[oi];
        } else {
          float t = v + bias[gn];
          float g = 0.5f * t * (1.0f + erff(t * 0.70710678118654752f));
          ((__hip_bfloat16*)Out)[oi] = __float2bfloat16(g);
        }
      }
    }
  }
}

// ---------------------------------------------------------------------------
// Attention (fp32 VALU, online softmax). qkv bf16 (B,S,1536): q|k|v each 512.
// grid: (32 q-tiles of 16 rows, NH, B), block 256 (4 waves x 4 rows each).
// K/V chunks of 64 keys staged in padded LDS (stride 65 -> conflict-free).
// ---------------------------------------------------------------------------
__global__ __launch_bounds__(256)
void attn_kernel(const __hip_bfloat16* __restrict__ qkv, __hip_bfloat16* __restrict__ o)
{
  const int qt = blockIdx.x;           // 16-row tile
  const int h = blockIdx.y, b = blockIdx.z;
  __shared__ float Qs[16 * 64];
  __shared__ float Ks[64 * 65];
  __shared__ float Vs[64 * 65];
  const int tid = threadIdx.x, lane = tid & 63, wave = tid >> 6;
  const size_t base = ((size_t)b * Ss) * 1536 + (size_t)h * 64;

  for (int idx = tid; idx < 16 * 64; idx += 256) {
    int r = idx >> 6, d = idx & 63;
    Qs[idx] = __bfloat162float(qkv[base + (size_t)(qt * 16 + r) * 1536 + d]);
  }

  float m0 = -1e30f, m1 = -1e30f, m2 = -1e30f, m3 = -1e30f;
  float l0 = 0.f, l1 = 0.f, l2 = 0.f, l3 = 0.f;
  float o0 = 0.f, o1 = 0.f, o2 = 0.f, o3 = 0.f;
  const int cmax = qt >> 2;            // last key-chunk index

  for (int c = 0; c <= cmax; ++c) {
    __syncthreads();
    for (int idx = tid; idx < 64 * 64; idx += 256) {
      int r = idx >> 6, d = idx & 63;
      size_t g = base + (size_t)(c * 64 + r) * 1536 + d;
      Ks[r * 65 + d] = __bfloat162float(qkv[g + 512]);
      Vs[r * 65 + d] = __bfloat162float(qkv[g + 1024]);
    }
    __syncthreads();
    const bool diag = (c == cmax);

    auto row_step = [&](int rr, float& mm, float& ll, float& oo) {
      int ql = wave * 4 + rr;          // row within 16-tile
      int qg = qt * 16 + ql;           // global seq row
      float s = 0.f;
      const float* qrow = Qs + ql * 64;
      #pragma unroll
      for (int d = 0; d < 64; ++d) s = fmaf(qrow[d], Ks[lane * 65 + d], s);
      s *= 0.125f;                     // DH^-0.5
      if (diag && (c * 64 + lane) > qg) s = -1e30f;
      float cm = s;
      #pragma unroll
      for (int off = 32; off; off >>= 1) cm = fmaxf(cm, __shfl_xor(cm, off));
      float mn = fmaxf(mm, cm);
      float alpha = __expf(mm - mn);
      float p = __expf(s - mn);
      float ps = p;
      #pragma unroll
      for (int off = 32; off; off >>= 1) ps += __shfl_xor(ps, off);
      ll = ll * alpha + ps;
      mm = mn;
      float oa = oo * alpha;
      #pragma unroll
      for (int j = 0; j < 64; ++j) oa = fmaf(__shfl(p, j), Vs[j * 65 + lane], oa);
      oo = oa;
    };
    row_step(0, m0, l0, o0);
    row_step(1, m1, l1, o1);
    row_step(2, m2, l2, o2);
    row_step(3, m3, l3, o3);
  }

  int qg0 = qt * 16 + wave * 4;
  o[((size_t)b * Ss + qg0 + 0) * INNERi + h * 64 + lane] = __float2bfloat16(o0 / l0);
  o[((size_t)b * Ss + qg0 + 1) * INNERi + h * 64 + lane] = __float2bfloat16(o1 / l1);
  o[((size_t)b * Ss + qg0 + 2) * INNERi + h * 64 + lane] = __float2bfloat16(o2 / l2);
  o[((size_t)b * Ss + qg0 + 3) * INNERi + h * 64 + lane] = __float2bfloat16(o3 / l3);
}

// ---------------------------------------------------------------------------
// Epilogue gather: out[b,d,sp] = x[b, 255+sp, d]
// ---------------------------------------------------------------------------
__global__ void epilogue_kernel(const float* __restrict__ x, float* __restrict__ out)
{
  int idx = blockIdx.x * 256 + threadIdx.x;    // over B*D*256
  int sp = idx & 255;
  int bd = idx >> 8;
  int b = bd >> 9, d = bd & 511;
  out[idx] = x[((size_t)b * Ss + (NCc - 1) + sp) * Dd + d];
}

// ---------------------------------------------------------------------------
extern "C" void kernel_launch(void* const* d_in, const int* in_sizes, int n_in,
                              void* d_out, int out_size, void* d_ws, size_t ws_size,
                              hipStream_t stream)
{
  const float* z       = (const float*)d_in[0];
  const float* slots   = (const float*)d_in[1];
  const float* pos_emb = (const float*)d_in[2];
  const float* spos    = (const float*)d_in[3];
  const float* norm_w  = (const float*)d_in[4];
  const float* norm_b  = (const float*)d_in[5];
  const float* ln1_w   = (const float*)d_in[6];
  const float* ln1_b   = (const float*)d_in[7];
  const float* qkv_w   = (const float*)d_in[8];
  const float* out_w   = (const float*)d_in[9];
  const float* out_b   = (const float*)d_in[10];
  const float* ln2_w   = (const float*)d_in[11];
  const float* ln2_b   = (const float*)d_in[12];
  const float* mlp_w1  = (const float*)d_in[13];
  const float* mlp_b1  = (const float*)d_in[14];
  const float* mlp_w2  = (const float*)d_in[15];
  const float* mlp_b2  = (const float*)d_in[16];

  char* ws = (char*)d_ws;
  // ws layout (bytes):
  //   xbuf  f32 : 0          .. 33,554,432
  //   ybuf  bf16: 33,554,432 .. 50,331,648
  //   big        : 50,331,648 .. 117,440,512  (qkv bf16 50.3MB | o bf16 16.8MB; h aliases all)
  //   wT    bf16: 117,440,512.. 167,772,160
  float*          xbuf = (float*)ws;
  __hip_bfloat16* ybuf = (__hip_bfloat16*)(ws + 33554432);
  __hip_bfloat16* qkvb = (__hip_bfloat16*)(ws + 50331648);
  __hip_bfloat16* obuf = (__hip_bfloat16*)(ws + 100663296);
  __hip_bfloat16* hbuf = (__hip_bfloat16*)(ws + 50331648);
  __hip_bfloat16* wT   = (__hip_bfloat16*)(ws + 117440512);

  const size_t WL = 3145728;   // bf16 elements per layer in wT
  // per-layer element offsets inside wT block:
  //   qkvT @0 (1536x512), outT @786432 (512x512), w1T @1048576 (2048x512), w2T @2097152 (512x2048)

  dim3 tb(32, 8);
  transpose_w<<<dim3(1536 / 32, 512 / 32, 8), tb, 0, stream>>>(qkv_w,  wT + 0,       512, 1536, (size_t)512 * 1536, WL);
  transpose_w<<<dim3(512 / 32,  512 / 32, 8), tb, 0, stream>>>(out_w,  wT + 786432,  512, 512,  (size_t)512 * 512,  WL);
  transpose_w<<<dim3(2048 / 32, 512 / 32, 8), tb, 0, stream>>>(mlp_w1, wT + 1048576, 512, 2048, (size_t)512 * 2048, WL);
  transpose_w<<<dim3(512 / 32, 2048 / 32, 8), tb, 0, stream>>>(mlp_w2, wT + 2097152, 2048, 512, (size_t)2048 * 512, WL);

  prologue_kernel<<<Mrows, 64, 0, stream>>>(z, slots, pos_emb, spos, norm_w, norm_b, xbuf);

  for (int i = 0; i < 8; ++i) {
    const __hip_bfloat16* qkvT = wT + (size_t)i * WL;
    const __hip_bfloat16* outT = wT + (size_t)i * WL + 786432;
    const __hip_bfloat16* w1T  = wT + (size_t)i * WL + 1048576;
    const __hip_bfloat16* w2T  = wT + (size_t)i * WL + 2097152;

    ln_kernel<<<Mrows / 4, 256, 0, stream>>>(xbuf, ln1_w + i * Dd, ln1_b + i * Dd, ybuf);
    gemm_bt<0><<<dim3(1536 / 128, Mrows / 128), 256, 0, stream>>>(
        ybuf, qkvT, nullptr, nullptr, qkvb, Mrows, 1536, 512);
    attn_kernel<<<dim3(32, NHh, Bb), 256, 0, stream>>>(qkvb, obuf);
    gemm_bt<1><<<dim3(512 / 128, Mrows / 128), 256, 0, stream>>>(
        obuf, outT, out_b + i * Dd, xbuf, xbuf, Mrows, 512, 512);
    ln_kernel<<<Mrows / 4, 256, 0, stream>>>(xbuf, ln2_w + i * Dd, ln2_b + i * Dd, ybuf);
    gemm_bt<2><<<dim3(2048 / 128, Mrows / 128), 256, 0, stream>>>(
        ybuf, w1T, mlp_b1 + i * MLPm, nullptr, hbuf, Mrows, 2048, 512);
    gemm_bt<1><<<dim3(512 / 128, Mrows / 128), 256, 0, stream>>>(
        hbuf, w2T, mlp_b2 + i * Dd, xbuf, xbuf, Mrows, 512, 2048);
  }

  epilogue_kernel<<<(Bb * Dd * 256) / 256, 256, 0, stream>>>(xbuf, (float*)d_out);
}

// Round 2
// 2453.767 us; speedup vs baseline: 4.5618x; 4.5618x over previous
//
#include <hip/hip_runtime.h>
#include <hip/hip_bf16.h>
#include <math.h>

// Problem constants
#define Bb 32
#define Dd 512
#define Ss 512      // NC + Hs*Ws
#define NHh 8
#define DHh 64
#define MLPm 2048
#define NCc 256
#define INNERi 512
#define Mrows (Bb*Ss)   // 16384

typedef __bf16 bf16x8 __attribute__((ext_vector_type(8)));
typedef float floatx4 __attribute__((ext_vector_type(4)));

__device__ __forceinline__ void load_lds16(const void* g, void* l) {
  __builtin_amdgcn_global_load_lds(
      (__attribute__((address_space(1))) void*)(g),
      (__attribute__((address_space(3))) void*)(l), 16, 0, 0);
}

// ---------------------------------------------------------------------------
// Tiled transpose + fp32->bf16 downcast: in (K,N) fp32 -> out (N,K) bf16
// ---------------------------------------------------------------------------
__global__ void transpose_w(const float* __restrict__ in, __hip_bfloat16* __restrict__ out,
                            int K, int N, size_t in_ls, size_t out_ls)
{
  __shared__ float tile[32][33];
  in  += (size_t)blockIdx.z * in_ls;
  out += (size_t)blockIdx.z * out_ls;
  int n0 = blockIdx.x * 32, k0 = blockIdx.y * 32;
  int tx = threadIdx.x;
  #pragma unroll
  for (int i = threadIdx.y; i < 32; i += 8)
    tile[i][tx] = in[(size_t)(k0 + i) * N + n0 + tx];
  __syncthreads();
  #pragma unroll
  for (int i = threadIdx.y; i < 32; i += 8)
    out[(size_t)(n0 + i) * K + k0 + tx] = __float2bfloat16(tile[tx][i]);
}

// ---------------------------------------------------------------------------
// Prologue: build x[b,s,:] (slots+slot_pos | z^T+pos), then LayerNorm(norm_w/b)
// ---------------------------------------------------------------------------
__global__ void prologue_kernel(const float* __restrict__ z, const float* __restrict__ slots,
                                const float* __restrict__ pos, const float* __restrict__ spos,
                                const float* __restrict__ nw, const float* __restrict__ nb,
                                float* __restrict__ x)
{
  int row = blockIdx.x;            // b*S + s
  int b = row >> 9, s = row & 511;
  int lane = threadIdx.x;
  float v[8];
  float sum = 0.f;
  #pragma unroll
  for (int j = 0; j < 8; ++j) {
    int d = lane + j * 64;
    float t;
    if (s < NCc) t = slots[((size_t)b * NCc + s) * Dd + d] + spos[(size_t)s * Dd + d];
    else {
      int sp = s - NCc;
      t = z[((size_t)b * Dd + d) * 256 + sp] + pos[(size_t)sp * Dd + d];
    }
    v[j] = t; sum += t;
  }
  #pragma unroll
  for (int o = 32; o; o >>= 1) sum += __shfl_xor(sum, o);
  float mean = sum * (1.f / Dd);
  float vs = 0.f;
  #pragma unroll
  for (int j = 0; j < 8; ++j) { float d = v[j] - mean; vs += d * d; }
  #pragma unroll
  for (int o = 32; o; o >>= 1) vs += __shfl_xor(vs, o);
  float rs = rsqrtf(vs * (1.f / Dd) + 1e-5f);
  #pragma unroll
  for (int j = 0; j < 8; ++j) {
    int d = lane + j * 64;
    x[(size_t)row * Dd + d] = (v[j] - mean) * rs * nw[d] + nb[d];
  }
}

// ---------------------------------------------------------------------------
// LayerNorm: x fp32 (rows,512) -> y bf16
// ---------------------------------------------------------------------------
__global__ void ln_kernel(const float* __restrict__ x, const float* __restrict__ w,
                          const float* __restrict__ b, __hip_bfloat16* __restrict__ y)
{
  int row = blockIdx.x * 4 + (threadIdx.x >> 6);
  int lane = threadIdx.x & 63;
  const float* xr = x + (size_t)row * Dd;
  float v[8];
  float sum = 0.f;
  #pragma unroll
  for (int j = 0; j < 8; ++j) { v[j] = xr[lane + j * 64]; sum += v[j]; }
  #pragma unroll
  for (int o = 32; o; o >>= 1) sum += __shfl_xor(sum, o);
  float mean = sum * (1.f / Dd);
  float vs = 0.f;
  #pragma unroll
  for (int j = 0; j < 8; ++j) { float d = v[j] - mean; vs += d * d; }
  #pragma unroll
  for (int o = 32; o; o >>= 1) vs += __shfl_xor(vs, o);
  float rs = rsqrtf(vs * (1.f / Dd) + 1e-5f);
  #pragma unroll
  for (int j = 0; j < 8; ++j) {
    int d = lane + j * 64;
    y[(size_t)row * Dd + d] = __float2bfloat16((v[j] - mean) * rs * w[d] + b[d]);
  }
}

// ---------------------------------------------------------------------------
// bf16 MFMA GEMM: C(M,N) = A(M,K) @ Bt(N,K)^T  [+bias] [+res] [gelu]
// MODE 0: -> bf16 out (no bias);  MODE 1: -> f32 out = acc+bias+res;
// MODE 2: -> bf16 out = gelu(acc+bias)
// ---------------------------------------------------------------------------
template <int MODE>
__global__ __launch_bounds__(256, 2)
void gemm_bt(const __hip_bfloat16* __restrict__ A, const __hip_bfloat16* __restrict__ Bt,
             const float* __restrict__ bias, const float* __restrict__ res,
             void* __restrict__ Out, int M, int N, int K)
{
  constexpr int BM = 128, BN = 128, BK = 64;
  __shared__ __align__(16) __hip_bfloat16 As[BM * BK];
  __shared__ __align__(16) __hip_bfloat16 Bs[BN * BK];
  const int tid = threadIdx.x;
  const int lane = tid & 63;
  const int wave = tid >> 6;
  const int m0 = blockIdx.y * BM;
  const int n0 = blockIdx.x * BN;
  const int wm = (wave & 1) * 64;
  const int wn = (wave >> 1) * 64;
  const int quad = lane >> 4;
  const int lrow = lane & 15;

  floatx4 acc[4][4];
  #pragma unroll
  for (int i = 0; i < 4; ++i)
    #pragma unroll
    for (int j = 0; j < 4; ++j) {
      floatx4 z4 = {0.f, 0.f, 0.f, 0.f};
      acc[i][j] = z4;
    }

  for (int k0 = 0; k0 < K; k0 += BK) {
    #pragma unroll
    for (int it = 0; it < 4; ++it) {
      int c = it * 256 + tid;
      int row = c >> 3, cc = c & 7;
      load_lds16(A + (size_t)(m0 + row) * K + k0 + cc * 8, As + c * 8);
    }
    #pragma unroll
    for (int it = 0; it < 4; ++it) {
      int c = it * 256 + tid;
      int row = c >> 3, cc = c & 7;
      load_lds16(Bt + (size_t)(n0 + row) * K + k0 + cc * 8, Bs + c * 8);
    }
    __syncthreads();

    #pragma unroll
    for (int k1 = 0; k1 < BK; k1 += 32) {
      bf16x8 a[4], b[4];
      #pragma unroll
      for (int i = 0; i < 4; ++i)
        a[i] = *reinterpret_cast<const bf16x8*>(&As[(wm + i * 16 + lrow) * BK + k1 + quad * 8]);
      #pragma unroll
      for (int i = 0; i < 4; ++i)
        b[i] = *reinterpret_cast<const bf16x8*>(&Bs[(wn + i * 16 + lrow) * BK + k1 + quad * 8]);
      #pragma unroll
      for (int mi = 0; mi < 4; ++mi)
        #pragma unroll
        for (int ni = 0; ni < 4; ++ni)
          acc[mi][ni] = __builtin_amdgcn_mfma_f32_16x16x32_bf16(a[mi], b[ni], acc[mi][ni], 0, 0, 0);
    }
    __syncthreads();
  }

  #pragma unroll
  for (int mi = 0; mi < 4; ++mi) {
    #pragma unroll
    for (int r = 0; r < 4; ++r) {
      int gm = m0 + wm + mi * 16 + quad * 4 + r;
      #pragma unroll
      for (int ni = 0; ni < 4; ++ni) {
        int gn = n0 + wn + ni * 16 + lrow;
        float v = acc[mi][ni][r];
        size_t oi = (size_t)gm * N + gn;
        if (MODE == 0) {
          ((__hip_bfloat16*)Out)[oi] = __float2bfloat16(v);
        } else if (MODE == 1) {
          ((float*)Out)[oi] = v + bias[gn] + res[oi];
        } else {
          float t = v + bias[gn];
          float g = 0.5f * t * (1.0f + erff(t * 0.70710678118654752f));
          ((__hip_bfloat16*)Out)[oi] = __float2bfloat16(g);
        }
      }
    }
  }
}

// ---------------------------------------------------------------------------
// MFMA flash attention. qkv bf16 (B,S,1536): q|k|v each 512, head offset h*64.
// Block: one (b,h,qt) with qt a 64-row q tile; 4 waves x 16 q-rows.
// Grid (8, NH, B). Key chunks of 64, causal => chunks 0..qt, diag masked.
// Fragment layouts (verified by working GEMM): A/B m=lane&15, k=quad*8+j;
// C/D row=quad*4+r, col=lane&15.
// ---------------------------------------------------------------------------
__global__ __launch_bounds__(256, 2)
void attn_mfma(const __hip_bfloat16* __restrict__ qkv, __hip_bfloat16* __restrict__ o)
{
  const int qt = blockIdx.x;           // 0..7
  const int h = blockIdx.y, b = blockIdx.z;
  __shared__ __align__(16) __hip_bfloat16 Qs[64 * 64];   // (qrow, dh)
  __shared__ __align__(16) __hip_bfloat16 Ks[64 * 64];   // (key, dh)
  __shared__ __align__(16) __hip_bfloat16 Vt[64 * 64];   // (dh, key)  TRANSPOSED
  __shared__ __align__(16) __hip_bfloat16 Ps[4][16 * 64];// per-wave P (qrow, key)

  const int tid = threadIdx.x, lane = tid & 63, wave = tid >> 6;
  const int quad = lane >> 4, col = lane & 15;
  const size_t base = ((size_t)b * Ss) * 1536 + (size_t)h * 64;

  // stage Q (64x64) via async global->LDS, 16B per lane, lane-linear LDS
  #pragma unroll
  for (int it = 0; it < 2; ++it) {
    int c = it * 256 + tid;
    int row = c >> 3, seg = c & 7;
    load_lds16(qkv + base + (size_t)(qt * 64 + row) * 1536 + seg * 8, Qs + c * 8);
  }

  float mrow[4] = {-1e30f, -1e30f, -1e30f, -1e30f};
  float lsum[4] = {0.f, 0.f, 0.f, 0.f};
  floatx4 accO[4];
  #pragma unroll
  for (int i = 0; i < 4; ++i) { floatx4 z4 = {0.f,0.f,0.f,0.f}; accO[i] = z4; }

  for (int c = 0; c <= qt; ++c) {
    __syncthreads();   // previous chunk's Ks/Vt reads done before restage
    // stage K chunk (64x64 row-major)
    #pragma unroll
    for (int it = 0; it < 2; ++it) {
      int cc = it * 256 + tid;
      int row = cc >> 3, seg = cc & 7;
      load_lds16(qkv + base + 512 + (size_t)(c * 64 + row) * 1536 + seg * 8, Ks + cc * 8);
    }
    // stage V transposed: thread reads 16B of a V row, writes 8 scalars strided.
    // row=lane => write bank = (row/2)%32 => 2-way conflict only (free).
    #pragma unroll
    for (int it = 0; it < 2; ++it) {
      int row = tid & 63;
      int seg = it * 4 + (tid >> 6);
      bf16x8 v8 = *reinterpret_cast<const bf16x8*>(
          qkv + base + 1024 + (size_t)(c * 64 + row) * 1536 + seg * 8);
      union { bf16x8 v; __hip_bfloat16 e[8]; } u; u.v = v8;
      #pragma unroll
      for (int j = 0; j < 8; ++j)
        Vt[(seg * 8 + j) * 64 + row] = u.e[j];
    }
    __syncthreads();   // drains vmcnt (global_load_lds) + lds writes

    // S = Q_wave(16x64) @ K(64x64)^T  -> 4 C-tiles over key
    floatx4 accS[4];
    #pragma unroll
    for (int i = 0; i < 4; ++i) { floatx4 z4 = {0.f,0.f,0.f,0.f}; accS[i] = z4; }
    #pragma unroll
    for (int kc = 0; kc < 2; ++kc) {
      bf16x8 aq = *reinterpret_cast<const bf16x8*>(&Qs[(wave * 16 + col) * 64 + kc * 32 + quad * 8]);
      #pragma unroll
      for (int ni = 0; ni < 4; ++ni) {
        bf16x8 bk = *reinterpret_cast<const bf16x8*>(&Ks[(ni * 16 + col) * 64 + kc * 32 + quad * 8]);
        accS[ni] = __builtin_amdgcn_mfma_f32_16x16x32_bf16(aq, bk, accS[ni], 0, 0, 0);
      }
    }

    // scale + causal mask (diag chunk only)
    const bool diag = (c == qt);
    float sc[4][4];   // [ni][r]
    #pragma unroll
    for (int ni = 0; ni < 4; ++ni)
      #pragma unroll
      for (int r = 0; r < 4; ++r) {
        float s = accS[ni][r] * 0.125f;
        if (diag) {
          int key = c * 64 + ni * 16 + col;
          int qg  = qt * 64 + wave * 16 + quad * 4 + r;
          if (key > qg) s = -1e30f;
        }
        sc[ni][r] = s;
      }

    // online softmax per row (rows live in 16-lane quad groups)
    #pragma unroll
    for (int r = 0; r < 4; ++r) {
      float cm = fmaxf(fmaxf(sc[0][r], sc[1][r]), fmaxf(sc[2][r], sc[3][r]));
      #pragma unroll
      for (int off = 1; off < 16; off <<= 1) cm = fmaxf(cm, __shfl_xor(cm, off));
      float mnew = fmaxf(mrow[r], cm);
      float alpha = __expf(mrow[r] - mnew);
      mrow[r] = mnew;
      float ps = 0.f;
      #pragma unroll
      for (int ni = 0; ni < 4; ++ni) {
        float pv = __expf(sc[ni][r] - mnew);
        sc[ni][r] = pv;
        ps += pv;
      }
      #pragma unroll
      for (int off = 1; off < 16; off <<= 1) ps += __shfl_xor(ps, off);
      lsum[r] = lsum[r] * alpha + ps;
      #pragma unroll
      for (int ni = 0; ni < 4; ++ni) accO[ni][r] *= alpha;
    }

    // P -> LDS (C layout -> row-major), then read back as A fragment
    #pragma unroll
    for (int ni = 0; ni < 4; ++ni)
      #pragma unroll
      for (int r = 0; r < 4; ++r)
        Ps[wave][(quad * 4 + r) * 64 + ni * 16 + col] = __float2bfloat16(sc[ni][r]);

    // O += P(16x64) @ Vt(64x64)^T   (Vt is (dh,key) so B-frag is contiguous)
    #pragma unroll
    for (int kc = 0; kc < 2; ++kc) {
      bf16x8 ap = *reinterpret_cast<const bf16x8*>(&Ps[wave][col * 64 + kc * 32 + quad * 8]);
      #pragma unroll
      for (int ni = 0; ni < 4; ++ni) {
        bf16x8 bv = *reinterpret_cast<const bf16x8*>(&Vt[(ni * 16 + col) * 64 + kc * 32 + quad * 8]);
        accO[ni] = __builtin_amdgcn_mfma_f32_16x16x32_bf16(ap, bv, accO[ni], 0, 0, 0);
      }
    }
  }

  // epilogue: O / l -> obuf (b, s, INNER) at head offset
  float inv[4];
  #pragma unroll
  for (int r = 0; r < 4; ++r) inv[r] = 1.f / lsum[r];
  #pragma unroll
  for (int ni = 0; ni < 4; ++ni)
    #pragma unroll
    for (int r = 0; r < 4; ++r) {
      int qg = qt * 64 + wave * 16 + quad * 4 + r;
      o[((size_t)b * Ss + qg) * INNERi + h * 64 + ni * 16 + col] =
          __float2bfloat16(accO[ni][r] * inv[r]);
    }
}

// ---------------------------------------------------------------------------
// Epilogue gather: out[b,d,sp] = x[b, 255+sp, d]
// ---------------------------------------------------------------------------
__global__ void epilogue_kernel(const float* __restrict__ x, float* __restrict__ out)
{
  int idx = blockIdx.x * 256 + threadIdx.x;    // over B*D*256
  int sp = idx & 255;
  int bd = idx >> 8;
  int b = bd >> 9, d = bd & 511;
  out[idx] = x[((size_t)b * Ss + (NCc - 1) + sp) * Dd + d];
}

// ---------------------------------------------------------------------------
extern "C" void kernel_launch(void* const* d_in, const int* in_sizes, int n_in,
                              void* d_out, int out_size, void* d_ws, size_t ws_size,
                              hipStream_t stream)
{
  const float* z       = (const float*)d_in[0];
  const float* slots   = (const float*)d_in[1];
  const float* pos_emb = (const float*)d_in[2];
  const float* spos    = (const float*)d_in[3];
  const float* norm_w  = (const float*)d_in[4];
  const float* norm_b  = (const float*)d_in[5];
  const float* ln1_w   = (const float*)d_in[6];
  const float* ln1_b   = (const float*)d_in[7];
  const float* qkv_w   = (const float*)d_in[8];
  const float* out_w   = (const float*)d_in[9];
  const float* out_b   = (const float*)d_in[10];
  const float* ln2_w   = (const float*)d_in[11];
  const float* ln2_b   = (const float*)d_in[12];
  const float* mlp_w1  = (const float*)d_in[13];
  const float* mlp_b1  = (const float*)d_in[14];
  const float* mlp_w2  = (const float*)d_in[15];
  const float* mlp_b2  = (const float*)d_in[16];

  char* ws = (char*)d_ws;
  float*          xbuf = (float*)ws;
  __hip_bfloat16* ybuf = (__hip_bfloat16*)(ws + 33554432);
  __hip_bfloat16* qkvb = (__hip_bfloat16*)(ws + 50331648);
  __hip_bfloat16* obuf = (__hip_bfloat16*)(ws + 100663296);
  __hip_bfloat16* hbuf = (__hip_bfloat16*)(ws + 50331648);
  __hip_bfloat16* wT   = (__hip_bfloat16*)(ws + 117440512);

  const size_t WL = 3145728;

  dim3 tb(32, 8);
  transpose_w<<<dim3(1536 / 32, 512 / 32, 8), tb, 0, stream>>>(qkv_w,  wT + 0,       512, 1536, (size_t)512 * 1536, WL);
  transpose_w<<<dim3(512 / 32,  512 / 32, 8), tb, 0, stream>>>(out_w,  wT + 786432,  512, 512,  (size_t)512 * 512,  WL);
  transpose_w<<<dim3(2048 / 32, 512 / 32, 8), tb, 0, stream>>>(mlp_w1, wT + 1048576, 512, 2048, (size_t)512 * 2048, WL);
  transpose_w<<<dim3(512 / 32, 2048 / 32, 8), tb, 0, stream>>>(mlp_w2, wT + 2097152, 2048, 512, (size_t)2048 * 512, WL);

  prologue_kernel<<<Mrows, 64, 0, stream>>>(z, slots, pos_emb, spos, norm_w, norm_b, xbuf);

  for (int i = 0; i < 8; ++i) {
    const __hip_bfloat16* qkvT = wT + (size_t)i * WL;
    const __hip_bfloat16* outT = wT + (size_t)i * WL + 786432;
    const __hip_bfloat16* w1T  = wT + (size_t)i * WL + 1048576;
    const __hip_bfloat16* w2T  = wT + (size_t)i * WL + 2097152;

    ln_kernel<<<Mrows / 4, 256, 0, stream>>>(xbuf, ln1_w + i * Dd, ln1_b + i * Dd, ybuf);
    gemm_bt<0><<<dim3(1536 / 128, Mrows / 128), 256, 0, stream>>>(
        ybuf, qkvT, nullptr, nullptr, qkvb, Mrows, 1536, 512);
    attn_mfma<<<dim3(8, NHh, Bb), 256, 0, stream>>>(qkvb, obuf);
    gemm_bt<1><<<dim3(512 / 128, Mrows / 128), 256, 0, stream>>>(
        obuf, outT, out_b + i * Dd, xbuf, xbuf, Mrows, 512, 512);
    ln_kernel<<<Mrows / 4, 256, 0, stream>>>(xbuf, ln2_w + i * Dd, ln2_b + i * Dd, ybuf);
    gemm_bt<2><<<dim3(2048 / 128, Mrows / 128), 256, 0, stream>>>(
        ybuf, w1T, mlp_b1 + i * MLPm, nullptr, hbuf, Mrows, 2048, 512);
    gemm_bt<1><<<dim3(512 / 128, Mrows / 128), 256, 0, stream>>>(
        hbuf, w2T, mlp_b2 + i * Dd, xbuf, xbuf, Mrows, 512, 2048);
  }

  epilogue_kernel<<<(Bb * Dd * 256) / 256, 256, 0, stream>>>(xbuf, (float*)d_out);
}

// Round 3
// 2112.759 us; speedup vs baseline: 5.2981x; 1.1614x over previous
//
#include <hip/hip_runtime.h>
#include <hip/hip_bf16.h>
#include <math.h>

// Problem constants
#define Bb 32
#define Dd 512
#define Ss 512      // NC + Hs*Ws
#define NHh 8
#define DHh 64
#define MLPm 2048
#define NCc 256
#define INNERi 512
#define Mrows (Bb*Ss)   // 16384

typedef __bf16 bf16x8 __attribute__((ext_vector_type(8)));
typedef float floatx4 __attribute__((ext_vector_type(4)));

__device__ __forceinline__ void load_lds16(const void* g, void* l) {
  __builtin_amdgcn_global_load_lds(
      (__attribute__((address_space(1))) void*)(g),
      (__attribute__((address_space(3))) void*)(l), 16, 0, 0);
}

// ---------------------------------------------------------------------------
// Tiled transpose + fp32->bf16 downcast: in (K,N) fp32 -> out (N,K) bf16
// ---------------------------------------------------------------------------
__global__ void transpose_w(const float* __restrict__ in, __hip_bfloat16* __restrict__ out,
                            int K, int N, size_t in_ls, size_t out_ls)
{
  __shared__ float tile[32][33];
  in  += (size_t)blockIdx.z * in_ls;
  out += (size_t)blockIdx.z * out_ls;
  int n0 = blockIdx.x * 32, k0 = blockIdx.y * 32;
  int tx = threadIdx.x;
  #pragma unroll
  for (int i = threadIdx.y; i < 32; i += 8)
    tile[i][tx] = in[(size_t)(k0 + i) * N + n0 + tx];
  __syncthreads();
  #pragma unroll
  for (int i = threadIdx.y; i < 32; i += 8)
    out[(size_t)(n0 + i) * K + k0 + tx] = __float2bfloat16(tile[tx][i]);
}

// ---------------------------------------------------------------------------
// Prologue: build x[b,s,:] (slots+slot_pos | z^T+pos), then LayerNorm(norm_w/b)
// ---------------------------------------------------------------------------
__global__ void prologue_kernel(const float* __restrict__ z, const float* __restrict__ slots,
                                const float* __restrict__ pos, const float* __restrict__ spos,
                                const float* __restrict__ nw, const float* __restrict__ nb,
                                float* __restrict__ x)
{
  int row = blockIdx.x;            // b*S + s
  int b = row >> 9, s = row & 511;
  int lane = threadIdx.x;
  float v[8];
  float sum = 0.f;
  #pragma unroll
  for (int j = 0; j < 8; ++j) {
    int d = lane + j * 64;
    float t;
    if (s < NCc) t = slots[((size_t)b * NCc + s) * Dd + d] + spos[(size_t)s * Dd + d];
    else {
      int sp = s - NCc;
      t = z[((size_t)b * Dd + d) * 256 + sp] + pos[(size_t)sp * Dd + d];
    }
    v[j] = t; sum += t;
  }
  #pragma unroll
  for (int o = 32; o; o >>= 1) sum += __shfl_xor(sum, o);
  float mean = sum * (1.f / Dd);
  float vs = 0.f;
  #pragma unroll
  for (int j = 0; j < 8; ++j) { float d = v[j] - mean; vs += d * d; }
  #pragma unroll
  for (int o = 32; o; o >>= 1) vs += __shfl_xor(vs, o);
  float rs = rsqrtf(vs * (1.f / Dd) + 1e-5f);
  #pragma unroll
  for (int j = 0; j < 8; ++j) {
    int d = lane + j * 64;
    x[(size_t)row * Dd + d] = (v[j] - mean) * rs * nw[d] + nb[d];
  }
}

// ---------------------------------------------------------------------------
// LayerNorm: x fp32 (rows,512) -> y bf16
// ---------------------------------------------------------------------------
__global__ void ln_kernel(const float* __restrict__ x, const float* __restrict__ w,
                          const float* __restrict__ b, __hip_bfloat16* __restrict__ y)
{
  int row = blockIdx.x * 4 + (threadIdx.x >> 6);
  int lane = threadIdx.x & 63;
  const float* xr = x + (size_t)row * Dd;
  float v[8];
  float sum = 0.f;
  #pragma unroll
  for (int j = 0; j < 8; ++j) { v[j] = xr[lane + j * 64]; sum += v[j]; }
  #pragma unroll
  for (int o = 32; o; o >>= 1) sum += __shfl_xor(sum, o);
  float mean = sum * (1.f / Dd);
  float vs = 0.f;
  #pragma unroll
  for (int j = 0; j < 8; ++j) { float d = v[j] - mean; vs += d * d; }
  #pragma unroll
  for (int o = 32; o; o >>= 1) vs += __shfl_xor(vs, o);
  float rs = rsqrtf(vs * (1.f / Dd) + 1e-5f);
  #pragma unroll
  for (int j = 0; j < 8; ++j) {
    int d = lane + j * 64;
    y[(size_t)row * Dd + d] = __float2bfloat16((v[j] - mean) * rs * w[d] + b[d]);
  }
}

// ---------------------------------------------------------------------------
// bf16 MFMA GEMM: C(M,N) = A(M,K) @ Bt(N,K)^T  [+bias] [+res] [gelu]
// MODE 0: -> bf16 out (no bias);  MODE 1: -> f32 out = acc+bias+res;
// MODE 2: -> bf16 out = gelu(acc+bias)
// ---------------------------------------------------------------------------
template <int MODE>
__global__ __launch_bounds__(256, 2)
void gemm_bt(const __hip_bfloat16* __restrict__ A, const __hip_bfloat16* __restrict__ Bt,
             const float* __restrict__ bias, const float* __restrict__ res,
             void* __restrict__ Out, int M, int N, int K)
{
  constexpr int BM = 128, BN = 128, BK = 64;
  __shared__ __align__(16) __hip_bfloat16 As[BM * BK];
  __shared__ __align__(16) __hip_bfloat16 Bs[BN * BK];
  const int tid = threadIdx.x;
  const int lane = tid & 63;
  const int wave = tid >> 6;
  const int m0 = blockIdx.y * BM;
  const int n0 = blockIdx.x * BN;
  const int wm = (wave & 1) * 64;
  const int wn = (wave >> 1) * 64;
  const int quad = lane >> 4;
  const int lrow = lane & 15;

  floatx4 acc[4][4];
  #pragma unroll
  for (int i = 0; i < 4; ++i)
    #pragma unroll
    for (int j = 0; j < 4; ++j) {
      floatx4 z4 = {0.f, 0.f, 0.f, 0.f};
      acc[i][j] = z4;
    }

  for (int k0 = 0; k0 < K; k0 += BK) {
    #pragma unroll
    for (int it = 0; it < 4; ++it) {
      int c = it * 256 + tid;
      int row = c >> 3, cc = c & 7;
      load_lds16(A + (size_t)(m0 + row) * K + k0 + cc * 8, As + c * 8);
    }
    #pragma unroll
    for (int it = 0; it < 4; ++it) {
      int c = it * 256 + tid;
      int row = c >> 3, cc = c & 7;
      load_lds16(Bt + (size_t)(n0 + row) * K + k0 + cc * 8, Bs + c * 8);
    }
    __syncthreads();

    #pragma unroll
    for (int k1 = 0; k1 < BK; k1 += 32) {
      bf16x8 a[4], b[4];
      #pragma unroll
      for (int i = 0; i < 4; ++i)
        a[i] = *reinterpret_cast<const bf16x8*>(&As[(wm + i * 16 + lrow) * BK + k1 + quad * 8]);
      #pragma unroll
      for (int i = 0; i < 4; ++i)
        b[i] = *reinterpret_cast<const bf16x8*>(&Bs[(wn + i * 16 + lrow) * BK + k1 + quad * 8]);
      #pragma unroll
      for (int mi = 0; mi < 4; ++mi)
        #pragma unroll
        for (int ni = 0; ni < 4; ++ni)
          acc[mi][ni] = __builtin_amdgcn_mfma_f32_16x16x32_bf16(a[mi], b[ni], acc[mi][ni], 0, 0, 0);
    }
    __syncthreads();
  }

  #pragma unroll
  for (int mi = 0; mi < 4; ++mi) {
    #pragma unroll
    for (int r = 0; r < 4; ++r) {
      int gm = m0 + wm + mi * 16 + quad * 4 + r;
      #pragma unroll
      for (int ni = 0; ni < 4; ++ni) {
        int gn = n0 + wn + ni * 16 + lrow;
        float v = acc[mi][ni][r];
        size_t oi = (size_t)gm * N + gn;
        if (MODE == 0) {
          ((__hip_bfloat16*)Out)[oi] = __float2bfloat16(v);
        } else if (MODE == 1) {
          ((float*)Out)[oi] = v + bias[gn] + res[oi];
        } else {
          float t = v + bias[gn];
          float g = 0.5f * t * (1.0f + erff(t * 0.70710678118654752f));
          ((__hip_bfloat16*)Out)[oi] = __float2bfloat16(g);
        }
      }
    }
  }
}

// ---------------------------------------------------------------------------
// Pair-balanced MFMA flash attention with XOR-swizzled LDS + reg prefetch.
// Block = (pair p, h, b) handles q-tiles {p, 7-p}: exactly 9 chunk-apps each.
// Grid (4, NH, B) = 1024 blocks of 256 (4 waves; each wave owns 16 q-rows of
// BOTH tiles). Key chunks of 64; K/V of chunk c+1 prefetched into VGPRs while
// computing chunk c.
// LDS element (row, k) stored at row*64 + ((k>>3 ^ (row&7))<<3) + (k&7):
// b128 frag reads hit all 32 banks (8-access b128 floor).
// Fragment layouts (verified): A/B m=lane&15, k=quad*8+j; C/D row=quad*4+r,
// col=lane&15.
// ---------------------------------------------------------------------------
__device__ __forceinline__ int swz(int row, int seg) {
  return row * 64 + (((seg) ^ (row & 7)) << 3);
}

__global__ __launch_bounds__(256, 2)
void attn_pair(const __hip_bfloat16* __restrict__ qkv, __hip_bfloat16* __restrict__ o)
{
  const int p = blockIdx.x;            // 0..3
  const int h = blockIdx.y, b = blockIdx.z;
  const int t0 = p, t1 = 7 - p;

  __shared__ __align__(16) __hip_bfloat16 Qs[2][64 * 64];
  __shared__ __align__(16) __hip_bfloat16 Ks[64 * 64];
  __shared__ __align__(16) __hip_bfloat16 Vt[64 * 64];   // (dh, key), swizzled
  __shared__ __align__(16) __hip_bfloat16 Ps[4][16 * 64];

  const int tid = threadIdx.x, lane = tid & 63, wave = tid >> 6;
  const int quad = lane >> 4, col = lane & 15;
  const size_t base = ((size_t)b * Ss) * 1536 + (size_t)h * 64;

  // stage Q for both tiles (swizzled)
  #pragma unroll
  for (int t = 0; t < 2; ++t) {
    const int tq = t ? t1 : t0;
    #pragma unroll
    for (int it = 0; it < 2; ++it) {
      int c = it * 256 + tid;
      int row = c >> 3, seg = c & 7;
      bf16x8 q8 = *reinterpret_cast<const bf16x8*>(
          qkv + base + (size_t)(tq * 64 + row) * 1536 + seg * 8);
      *reinterpret_cast<bf16x8*>(&Qs[t][swz(row, seg)]) = q8;
    }
  }

  bf16x8 kreg[2], vreg[2];
  auto load_kv = [&](int c0) {
    #pragma unroll
    for (int it = 0; it < 2; ++it) {
      int c = it * 256 + tid;
      kreg[it] = *reinterpret_cast<const bf16x8*>(
          qkv + base + 512 + (size_t)(c0 * 64 + (c >> 3)) * 1536 + (c & 7) * 8);
    }
    #pragma unroll
    for (int it = 0; it < 2; ++it) {
      int row = tid & 63, seg = it * 4 + wave;
      vreg[it] = *reinterpret_cast<const bf16x8*>(
          qkv + base + 1024 + (size_t)(c0 * 64 + row) * 1536 + seg * 8);
    }
  };
  auto store_kv = [&]() {
    #pragma unroll
    for (int it = 0; it < 2; ++it) {
      int c = it * 256 + tid;
      *reinterpret_cast<bf16x8*>(&Ks[swz(c >> 3, c & 7)]) = kreg[it];
    }
    #pragma unroll
    for (int it = 0; it < 2; ++it) {
      int row = tid & 63, seg = it * 4 + wave;
      union { bf16x8 v; __hip_bfloat16 e[8]; } u; u.v = vreg[it];
      #pragma unroll
      for (int j = 0; j < 8; ++j) {
        int d = seg * 8 + j;
        Vt[d * 64 + ((((row >> 3)) ^ (d & 7)) << 3) + (row & 7)] = u.e[j];
      }
    }
  };

  float  mrow[2][4], lsum[2][4];
  floatx4 accO[2][4];
  #pragma unroll
  for (int t = 0; t < 2; ++t)
    #pragma unroll
    for (int r = 0; r < 4; ++r) {
      mrow[t][r] = -1e30f; lsum[t][r] = 0.f;
      floatx4 z4 = {0.f, 0.f, 0.f, 0.f};
      accO[t][r] = z4;
    }

  auto compute_tile = [&](const __hip_bfloat16* Qt, int tq, int c,
                          float* mr, float* ls, floatx4* aO) {
    floatx4 accS[4];
    #pragma unroll
    for (int i = 0; i < 4; ++i) { floatx4 z4 = {0.f,0.f,0.f,0.f}; accS[i] = z4; }
    const int m = wave * 16 + col;
    #pragma unroll
    for (int kc = 0; kc < 2; ++kc) {
      bf16x8 aq = *reinterpret_cast<const bf16x8*>(&Qt[swz(m, kc * 4 + quad)]);
      #pragma unroll
      for (int ni = 0; ni < 4; ++ni) {
        bf16x8 bk = *reinterpret_cast<const bf16x8*>(&Ks[swz(ni * 16 + col, kc * 4 + quad)]);
        accS[ni] = __builtin_amdgcn_mfma_f32_16x16x32_bf16(aq, bk, accS[ni], 0, 0, 0);
      }
    }

    const bool diag = (c == tq);
    float sc[4][4];
    #pragma unroll
    for (int ni = 0; ni < 4; ++ni)
      #pragma unroll
      for (int r = 0; r < 4; ++r) {
        float s = accS[ni][r] * 0.125f;
        if (diag && (ni * 16 + col) > (wave * 16 + quad * 4 + r)) s = -1e30f;
        sc[ni][r] = s;
      }

    #pragma unroll
    for (int r = 0; r < 4; ++r) {
      float cm = fmaxf(fmaxf(sc[0][r], sc[1][r]), fmaxf(sc[2][r], sc[3][r]));
      #pragma unroll
      for (int off = 1; off < 16; off <<= 1) cm = fmaxf(cm, __shfl_xor(cm, off));
      float mnew = fmaxf(mr[r], cm);
      float alpha = __expf(mr[r] - mnew);
      mr[r] = mnew;
      float ps = 0.f;
      #pragma unroll
      for (int ni = 0; ni < 4; ++ni) {
        float pv = __expf(sc[ni][r] - mnew);
        sc[ni][r] = pv;
        ps += pv;
      }
      #pragma unroll
      for (int off = 1; off < 16; off <<= 1) ps += __shfl_xor(ps, off);
      ls[r] = ls[r] * alpha + ps;
      #pragma unroll
      for (int ni = 0; ni < 4; ++ni) aO[ni][r] *= alpha;
    }

    // P (C layout) -> swizzled row-major in per-wave LDS
    #pragma unroll
    for (int ni = 0; ni < 4; ++ni)
      #pragma unroll
      for (int r = 0; r < 4; ++r) {
        int prow = quad * 4 + r;
        int pseg = ni * 2 + (col >> 3);
        Ps[wave][prow * 64 + ((pseg ^ (prow & 7)) << 3) + (col & 7)] =
            __float2bfloat16(sc[ni][r]);
      }

    #pragma unroll
    for (int kc = 0; kc < 2; ++kc) {
      bf16x8 ap = *reinterpret_cast<const bf16x8*>(&Ps[wave][swz(col, kc * 4 + quad)]);
      #pragma unroll
      for (int ni = 0; ni < 4; ++ni) {
        bf16x8 bv = *reinterpret_cast<const bf16x8*>(&Vt[swz(ni * 16 + col, kc * 4 + quad)]);
        aO[ni] = __builtin_amdgcn_mfma_f32_16x16x32_bf16(ap, bv, aO[ni], 0, 0, 0);
      }
    }
  };

  load_kv(0);
  for (int c = 0; c <= t1; ++c) {
    __syncthreads();                 // previous chunk's LDS reads complete
    store_kv();
    __syncthreads();                 // K/V (and Q, first iter) visible
    if (c < t1) load_kv(c + 1);      // prefetch; drains at next store_kv
    compute_tile(Qs[1], t1, c, mrow[1], lsum[1], accO[1]);
    if (c <= t0) compute_tile(Qs[0], t0, c, mrow[0], lsum[0], accO[0]);
  }

  #pragma unroll
  for (int t = 0; t < 2; ++t) {
    const int tq = t ? t1 : t0;
    float inv[4];
    #pragma unroll
    for (int r = 0; r < 4; ++r) inv[r] = 1.f / lsum[t][r];
    #pragma unroll
    for (int ni = 0; ni < 4; ++ni)
      #pragma unroll
      for (int r = 0; r < 4; ++r) {
        int qg = tq * 64 + wave * 16 + quad * 4 + r;
        o[((size_t)b * Ss + qg) * INNERi + h * 64 + ni * 16 + col] =
            __float2bfloat16(accO[t][ni][r] * inv[r]);
      }
  }
}

// ---------------------------------------------------------------------------
// Epilogue gather: out[b,d,sp] = x[b, 255+sp, d]
// ---------------------------------------------------------------------------
__global__ void epilogue_kernel(const float* __restrict__ x, float* __restrict__ out)
{
  int idx = blockIdx.x * 256 + threadIdx.x;    // over B*D*256
  int sp = idx & 255;
  int bd = idx >> 8;
  int b = bd >> 9, d = bd & 511;
  out[idx] = x[((size_t)b * Ss + (NCc - 1) + sp) * Dd + d];
}

// ---------------------------------------------------------------------------
extern "C" void kernel_launch(void* const* d_in, const int* in_sizes, int n_in,
                              void* d_out, int out_size, void* d_ws, size_t ws_size,
                              hipStream_t stream)
{
  const float* z       = (const float*)d_in[0];
  const float* slots   = (const float*)d_in[1];
  const float* pos_emb = (const float*)d_in[2];
  const float* spos    = (const float*)d_in[3];
  const float* norm_w  = (const float*)d_in[4];
  const float* norm_b  = (const float*)d_in[5];
  const float* ln1_w   = (const float*)d_in[6];
  const float* ln1_b   = (const float*)d_in[7];
  const float* qkv_w   = (const float*)d_in[8];
  const float* out_w   = (const float*)d_in[9];
  const float* out_b   = (const float*)d_in[10];
  const float* ln2_w   = (const float*)d_in[11];
  const float* ln2_b   = (const float*)d_in[12];
  const float* mlp_w1  = (const float*)d_in[13];
  const float* mlp_b1  = (const float*)d_in[14];
  const float* mlp_w2  = (const float*)d_in[15];
  const float* mlp_b2  = (const float*)d_in[16];

  char* ws = (char*)d_ws;
  float*          xbuf = (float*)ws;
  __hip_bfloat16* ybuf = (__hip_bfloat16*)(ws + 33554432);
  __hip_bfloat16* qkvb = (__hip_bfloat16*)(ws + 50331648);
  __hip_bfloat16* obuf = (__hip_bfloat16*)(ws + 100663296);
  __hip_bfloat16* hbuf = (__hip_bfloat16*)(ws + 50331648);
  __hip_bfloat16* wT   = (__hip_bfloat16*)(ws + 117440512);

  const size_t WL = 3145728;

  dim3 tb(32, 8);
  transpose_w<<<dim3(1536 / 32, 512 / 32, 8), tb, 0, stream>>>(qkv_w,  wT + 0,       512, 1536, (size_t)512 * 1536, WL);
  transpose_w<<<dim3(512 / 32,  512 / 32, 8), tb, 0, stream>>>(out_w,  wT + 786432,  512, 512,  (size_t)512 * 512,  WL);
  transpose_w<<<dim3(2048 / 32, 512 / 32, 8), tb, 0, stream>>>(mlp_w1, wT + 1048576, 512, 2048, (size_t)512 * 2048, WL);
  transpose_w<<<dim3(512 / 32, 2048 / 32, 8), tb, 0, stream>>>(mlp_w2, wT + 2097152, 2048, 512, (size_t)2048 * 512, WL);

  prologue_kernel<<<Mrows, 64, 0, stream>>>(z, slots, pos_emb, spos, norm_w, norm_b, xbuf);

  for (int i = 0; i < 8; ++i) {
    const __hip_bfloat16* qkvT = wT + (size_t)i * WL;
    const __hip_bfloat16* outT = wT + (size_t)i * WL + 786432;
    const __hip_bfloat16* w1T  = wT + (size_t)i * WL + 1048576;
    const __hip_bfloat16* w2T  = wT + (size_t)i * WL + 2097152;

    ln_kernel<<<Mrows / 4, 256, 0, stream>>>(xbuf, ln1_w + i * Dd, ln1_b + i * Dd, ybuf);
    gemm_bt<0><<<dim3(1536 / 128, Mrows / 128), 256, 0, stream>>>(
        ybuf, qkvT, nullptr, nullptr, qkvb, Mrows, 1536, 512);
    attn_pair<<<dim3(4, NHh, Bb), 256, 0, stream>>>(qkvb, obuf);
    gemm_bt<1><<<dim3(512 / 128, Mrows / 128), 256, 0, stream>>>(
        obuf, outT, out_b + i * Dd, xbuf, xbuf, Mrows, 512, 512);
    ln_kernel<<<Mrows / 4, 256, 0, stream>>>(xbuf, ln2_w + i * Dd, ln2_b + i * Dd, ybuf);
    gemm_bt<2><<<dim3(2048 / 128, Mrows / 128), 256, 0, stream>>>(
        ybuf, w1T, mlp_b1 + i * MLPm, nullptr, hbuf, Mrows, 2048, 512);
    gemm_bt<1><<<dim3(512 / 128, Mrows / 128), 256, 0, stream>>>(
        hbuf, w2T, mlp_b2 + i * Dd, xbuf, xbuf, Mrows, 512, 2048);
  }

  epilogue_kernel<<<(Bb * Dd * 256) / 256, 256, 0, stream>>>(xbuf, (float*)d_out);
}

// Round 4
// 1829.773 us; speedup vs baseline: 6.1175x; 1.1547x over previous
//
#include <hip/hip_runtime.h>
#include <hip/hip_bf16.h>
#include <math.h>

// Problem constants
#define Bb 32
#define Dd 512
#define Ss 512      // NC + Hs*Ws
#define NHh 8
#define DHh 64
#define MLPm 2048
#define NCc 256
#define INNERi 512
#define Mrows (Bb*Ss)   // 16384

typedef __bf16 bf16x8 __attribute__((ext_vector_type(8)));
typedef float floatx4 __attribute__((ext_vector_type(4)));

__device__ __forceinline__ void load_lds16(const void* g, void* l) {
  __builtin_amdgcn_global_load_lds(
      (__attribute__((address_space(1))) void*)(g),
      (__attribute__((address_space(3))) void*)(l), 16, 0, 0);
}

// XOR-swizzled LDS addressing for 64-elem bf16 rows: logical (row, seg8)
// stored at row*64 + ((seg ^ (row&7))<<3). b128 frag reads spread banks.
__device__ __forceinline__ int swz(int row, int seg) {
  return row * 64 + (((seg) ^ (row & 7)) << 3);
}

// ---------------------------------------------------------------------------
// Tiled transpose + fp32->bf16 downcast: in (K,N) fp32 -> out (N,K) bf16
// ---------------------------------------------------------------------------
__global__ void transpose_w(const float* __restrict__ in, __hip_bfloat16* __restrict__ out,
                            int K, int N, size_t in_ls, size_t out_ls)
{
  __shared__ float tile[32][33];
  in  += (size_t)blockIdx.z * in_ls;
  out += (size_t)blockIdx.z * out_ls;
  int n0 = blockIdx.x * 32, k0 = blockIdx.y * 32;
  int tx = threadIdx.x;
  #pragma unroll
  for (int i = threadIdx.y; i < 32; i += 8)
    tile[i][tx] = in[(size_t)(k0 + i) * N + n0 + tx];
  __syncthreads();
  #pragma unroll
  for (int i = threadIdx.y; i < 32; i += 8)
    out[(size_t)(n0 + i) * K + k0 + tx] = __float2bfloat16(tile[tx][i]);
}

// ---------------------------------------------------------------------------
// Prologue: build x[b,s,:] (slots+slot_pos | z^T+pos), then LayerNorm(norm_w/b)
// ---------------------------------------------------------------------------
__global__ void prologue_kernel(const float* __restrict__ z, const float* __restrict__ slots,
                                const float* __restrict__ pos, const float* __restrict__ spos,
                                const float* __restrict__ nw, const float* __restrict__ nb,
                                float* __restrict__ x)
{
  int row = blockIdx.x;            // b*S + s
  int b = row >> 9, s = row & 511;
  int lane = threadIdx.x;
  float v[8];
  float sum = 0.f;
  #pragma unroll
  for (int j = 0; j < 8; ++j) {
    int d = lane + j * 64;
    float t;
    if (s < NCc) t = slots[((size_t)b * NCc + s) * Dd + d] + spos[(size_t)s * Dd + d];
    else {
      int sp = s - NCc;
      t = z[((size_t)b * Dd + d) * 256 + sp] + pos[(size_t)sp * Dd + d];
    }
    v[j] = t; sum += t;
  }
  #pragma unroll
  for (int o = 32; o; o >>= 1) sum += __shfl_xor(sum, o);
  float mean = sum * (1.f / Dd);
  float vs = 0.f;
  #pragma unroll
  for (int j = 0; j < 8; ++j) { float d = v[j] - mean; vs += d * d; }
  #pragma unroll
  for (int o = 32; o; o >>= 1) vs += __shfl_xor(vs, o);
  float rs = rsqrtf(vs * (1.f / Dd) + 1e-5f);
  #pragma unroll
  for (int j = 0; j < 8; ++j) {
    int d = lane + j * 64;
    x[(size_t)row * Dd + d] = (v[j] - mean) * rs * nw[d] + nb[d];
  }
}

// ---------------------------------------------------------------------------
// LayerNorm: x fp32 (rows,512) -> y bf16
// ---------------------------------------------------------------------------
__global__ void ln_kernel(const float* __restrict__ x, const float* __restrict__ w,
                          const float* __restrict__ b, __hip_bfloat16* __restrict__ y)
{
  int row = blockIdx.x * 4 + (threadIdx.x >> 6);
  int lane = threadIdx.x & 63;
  const float* xr = x + (size_t)row * Dd;
  float v[8];
  float sum = 0.f;
  #pragma unroll
  for (int j = 0; j < 8; ++j) { v[j] = xr[lane + j * 64]; sum += v[j]; }
  #pragma unroll
  for (int o = 32; o; o >>= 1) sum += __shfl_xor(sum, o);
  float mean = sum * (1.f / Dd);
  float vs = 0.f;
  #pragma unroll
  for (int j = 0; j < 8; ++j) { float d = v[j] - mean; vs += d * d; }
  #pragma unroll
  for (int o = 32; o; o >>= 1) vs += __shfl_xor(vs, o);
  float rs = rsqrtf(vs * (1.f / Dd) + 1e-5f);
  #pragma unroll
  for (int j = 0; j < 8; ++j) {
    int d = lane + j * 64;
    y[(size_t)row * Dd + d] = __float2bfloat16((v[j] - mean) * rs * w[d] + b[d]);
  }
}

// ---------------------------------------------------------------------------
// bf16 MFMA GEMM: C(M,N) = A(M,K) @ Bt(N,K)^T  [+bias] [+res] [gelu]
// MODE 0: -> bf16 out (no bias);  MODE 1: -> f32 out = acc+bias+res;
// MODE 2: -> bf16 out = gelu(acc+bias)
// 1-D grid (N/128)*(M/128) with XCD swizzle: xcd=bid&7 owns M-tiles
// {xcd, xcd+8, ...}; consecutive blocks sweep N for one M-tile (A stays in
// that XCD's L2). LDS tiles XOR-swizzled via permuted glds source segs.
// ---------------------------------------------------------------------------
template <int MODE>
__global__ __launch_bounds__(256, 2)
void gemm_bt(const __hip_bfloat16* __restrict__ A, const __hip_bfloat16* __restrict__ Bt,
             const float* __restrict__ bias, const float* __restrict__ res,
             void* __restrict__ Out, int M, int N, int K)
{
  constexpr int BM = 128, BN = 128, BK = 64;
  __shared__ __align__(16) __hip_bfloat16 As[BM * BK];
  __shared__ __align__(16) __hip_bfloat16 Bs[BN * BK];
  const int tid = threadIdx.x;
  const int lane = tid & 63;
  const int wave = tid >> 6;

  // XCD-aware block swizzle (bid%8 -> XCD heuristic; neutral if mapping differs)
  const int NBLK = N >> 7;
  const int bid = blockIdx.x;
  const int xcd = bid & 7;
  const int j = bid >> 3;
  const int nb = j % NBLK;
  const int mt = xcd + ((j / NBLK) << 3);
  const int m0 = mt << 7;
  const int n0 = nb << 7;

  const int wm = (wave & 1) * 64;
  const int wn = (wave >> 1) * 64;
  const int quad = lane >> 4;
  const int lrow = lane & 15;

  floatx4 acc[4][4];
  #pragma unroll
  for (int i = 0; i < 4; ++i)
    #pragma unroll
    for (int jj = 0; jj < 4; ++jj) {
      floatx4 z4 = {0.f, 0.f, 0.f, 0.f};
      acc[i][jj] = z4;
    }

  for (int k0 = 0; k0 < K; k0 += BK) {
    // stage tiles via glds; LDS chunk c is lane-linear (DMA constraint), the
    // GLOBAL segment is XOR-permuted so the LDS layout lands swizzled.
    #pragma unroll
    for (int it = 0; it < 4; ++it) {
      int c = it * 256 + tid;
      int row = c >> 3, seg = (c & 7) ^ (row & 7);
      load_lds16(A + (size_t)(m0 + row) * K + k0 + seg * 8, As + c * 8);
    }
    #pragma unroll
    for (int it = 0; it < 4; ++it) {
      int c = it * 256 + tid;
      int row = c >> 3, seg = (c & 7) ^ (row & 7);
      load_lds16(Bt + (size_t)(n0 + row) * K + k0 + seg * 8, Bs + c * 8);
    }
    __syncthreads();

    #pragma unroll
    for (int k1 = 0; k1 < BK; k1 += 32) {
      const int s0 = k1 >> 3;   // 0 or 4
      bf16x8 a[4], b[4];
      #pragma unroll
      for (int i = 0; i < 4; ++i)
        a[i] = *reinterpret_cast<const bf16x8*>(&As[swz(wm + i * 16 + lrow, s0 + quad)]);
      #pragma unroll
      for (int i = 0; i < 4; ++i)
        b[i] = *reinterpret_cast<const bf16x8*>(&Bs[swz(wn + i * 16 + lrow, s0 + quad)]);
      #pragma unroll
      for (int mi = 0; mi < 4; ++mi)
        #pragma unroll
        for (int ni = 0; ni < 4; ++ni)
          acc[mi][ni] = __builtin_amdgcn_mfma_f32_16x16x32_bf16(a[mi], b[ni], acc[mi][ni], 0, 0, 0);
    }
    __syncthreads();
  }

  #pragma unroll
  for (int mi = 0; mi < 4; ++mi) {
    #pragma unroll
    for (int r = 0; r < 4; ++r) {
      int gm = m0 + wm + mi * 16 + quad * 4 + r;
      #pragma unroll
      for (int ni = 0; ni < 4; ++ni) {
        int gn = n0 + wn + ni * 16 + lrow;
        float v = acc[mi][ni][r];
        size_t oi = (size_t)gm * N + gn;
        if (MODE == 0) {
          ((__hip_bfloat16*)Out)[oi] = __float2bfloat16(v);
        } else if (MODE == 1) {
          ((float*)Out)[oi] = v + bias[gn] + res[oi];
        } else {
          float t = v + bias[gn];
          float g = 0.5f * t * (1.0f + erff(t * 0.70710678118654752f));
          ((__hip_bfloat16*)Out)[oi] = __float2bfloat16(g);
        }
      }
    }
  }
}

// ---------------------------------------------------------------------------
// Pair-balanced MFMA flash attention with XOR-swizzled LDS + reg prefetch.
// ---------------------------------------------------------------------------
__global__ __launch_bounds__(256, 2)
void attn_pair(const __hip_bfloat16* __restrict__ qkv, __hip_bfloat16* __restrict__ o)
{
  const int p = blockIdx.x;            // 0..3
  const int h = blockIdx.y, b = blockIdx.z;
  const int t0 = p, t1 = 7 - p;

  __shared__ __align__(16) __hip_bfloat16 Qs[2][64 * 64];
  __shared__ __align__(16) __hip_bfloat16 Ks[64 * 64];
  __shared__ __align__(16) __hip_bfloat16 Vt[64 * 64];   // (dh, key), swizzled
  __shared__ __align__(16) __hip_bfloat16 Ps[4][16 * 64];

  const int tid = threadIdx.x, lane = tid & 63, wave = tid >> 6;
  const int quad = lane >> 4, col = lane & 15;
  const size_t base = ((size_t)b * Ss) * 1536 + (size_t)h * 64;

  // stage Q for both tiles (swizzled)
  #pragma unroll
  for (int t = 0; t < 2; ++t) {
    const int tq = t ? t1 : t0;
    #pragma unroll
    for (int it = 0; it < 2; ++it) {
      int c = it * 256 + tid;
      int row = c >> 3, seg = c & 7;
      bf16x8 q8 = *reinterpret_cast<const bf16x8*>(
          qkv + base + (size_t)(tq * 64 + row) * 1536 + seg * 8);
      *reinterpret_cast<bf16x8*>(&Qs[t][swz(row, seg)]) = q8;
    }
  }

  bf16x8 kreg[2], vreg[2];
  auto load_kv = [&](int c0) {
    #pragma unroll
    for (int it = 0; it < 2; ++it) {
      int c = it * 256 + tid;
      kreg[it] = *reinterpret_cast<const bf16x8*>(
          qkv + base + 512 + (size_t)(c0 * 64 + (c >> 3)) * 1536 + (c & 7) * 8);
    }
    #pragma unroll
    for (int it = 0; it < 2; ++it) {
      int row = tid & 63, seg = it * 4 + wave;
      vreg[it] = *reinterpret_cast<const bf16x8*>(
          qkv + base + 1024 + (size_t)(c0 * 64 + row) * 1536 + seg * 8);
    }
  };
  auto store_kv = [&]() {
    #pragma unroll
    for (int it = 0; it < 2; ++it) {
      int c = it * 256 + tid;
      *reinterpret_cast<bf16x8*>(&Ks[swz(c >> 3, c & 7)]) = kreg[it];
    }
    #pragma unroll
    for (int it = 0; it < 2; ++it) {
      int row = tid & 63, seg = it * 4 + wave;
      union { bf16x8 v; __hip_bfloat16 e[8]; } u; u.v = vreg[it];
      #pragma unroll
      for (int j = 0; j < 8; ++j) {
        int d = seg * 8 + j;
        Vt[d * 64 + ((((row >> 3)) ^ (d & 7)) << 3) + (row & 7)] = u.e[j];
      }
    }
  };

  float  mrow[2][4], lsum[2][4];
  floatx4 accO[2][4];
  #pragma unroll
  for (int t = 0; t < 2; ++t)
    #pragma unroll
    for (int r = 0; r < 4; ++r) {
      mrow[t][r] = -1e30f; lsum[t][r] = 0.f;
      floatx4 z4 = {0.f, 0.f, 0.f, 0.f};
      accO[t][r] = z4;
    }

  auto compute_tile = [&](const __hip_bfloat16* Qt, int tq, int c,
                          float* mr, float* ls, floatx4* aO) {
    floatx4 accS[4];
    #pragma unroll
    for (int i = 0; i < 4; ++i) { floatx4 z4 = {0.f,0.f,0.f,0.f}; accS[i] = z4; }
    const int m = wave * 16 + col;
    #pragma unroll
    for (int kc = 0; kc < 2; ++kc) {
      bf16x8 aq = *reinterpret_cast<const bf16x8*>(&Qt[swz(m, kc * 4 + quad)]);
      #pragma unroll
      for (int ni = 0; ni < 4; ++ni) {
        bf16x8 bk = *reinterpret_cast<const bf16x8*>(&Ks[swz(ni * 16 + col, kc * 4 + quad)]);
        accS[ni] = __builtin_amdgcn_mfma_f32_16x16x32_bf16(aq, bk, accS[ni], 0, 0, 0);
      }
    }

    const bool diag = (c == tq);
    float sc[4][4];
    #pragma unroll
    for (int ni = 0; ni < 4; ++ni)
      #pragma unroll
      for (int r = 0; r < 4; ++r) {
        float s = accS[ni][r] * 0.125f;
        if (diag && (ni * 16 + col) > (wave * 16 + quad * 4 + r)) s = -1e30f;
        sc[ni][r] = s;
      }

    #pragma unroll
    for (int r = 0; r < 4; ++r) {
      float cm = fmaxf(fmaxf(sc[0][r], sc[1][r]), fmaxf(sc[2][r], sc[3][r]));
      #pragma unroll
      for (int off = 1; off < 16; off <<= 1) cm = fmaxf(cm, __shfl_xor(cm, off));
      float mnew = fmaxf(mr[r], cm);
      float alpha = __expf(mr[r] - mnew);
      mr[r] = mnew;
      float ps = 0.f;
      #pragma unroll
      for (int ni = 0; ni < 4; ++ni) {
        float pv = __expf(sc[ni][r] - mnew);
        sc[ni][r] = pv;
        ps += pv;
      }
      #pragma unroll
      for (int off = 1; off < 16; off <<= 1) ps += __shfl_xor(ps, off);
      ls[r] = ls[r] * alpha + ps;
      #pragma unroll
      for (int ni = 0; ni < 4; ++ni) aO[ni][r] *= alpha;
    }

    #pragma unroll
    for (int ni = 0; ni < 4; ++ni)
      #pragma unroll
      for (int r = 0; r < 4; ++r) {
        int prow = quad * 4 + r;
        int pseg = ni * 2 + (col >> 3);
        Ps[wave][prow * 64 + ((pseg ^ (prow & 7)) << 3) + (col & 7)] =
            __float2bfloat16(sc[ni][r]);
      }

    #pragma unroll
    for (int kc = 0; kc < 2; ++kc) {
      bf16x8 ap = *reinterpret_cast<const bf16x8*>(&Ps[wave][swz(col, kc * 4 + quad)]);
      #pragma unroll
      for (int ni = 0; ni < 4; ++ni) {
        bf16x8 bv = *reinterpret_cast<const bf16x8*>(&Vt[swz(ni * 16 + col, kc * 4 + quad)]);
        aO[ni] = __builtin_amdgcn_mfma_f32_16x16x32_bf16(ap, bv, aO[ni], 0, 0, 0);
      }
    }
  };

  load_kv(0);
  for (int c = 0; c <= t1; ++c) {
    __syncthreads();
    store_kv();
    __syncthreads();
    if (c < t1) load_kv(c + 1);
    compute_tile(Qs[1], t1, c, mrow[1], lsum[1], accO[1]);
    if (c <= t0) compute_tile(Qs[0], t0, c, mrow[0], lsum[0], accO[0]);
  }

  #pragma unroll
  for (int t = 0; t < 2; ++t) {
    const int tq = t ? t1 : t0;
    float inv[4];
    #pragma unroll
    for (int r = 0; r < 4; ++r) inv[r] = 1.f / lsum[t][r];
    #pragma unroll
    for (int ni = 0; ni < 4; ++ni)
      #pragma unroll
      for (int r = 0; r < 4; ++r) {
        int qg = tq * 64 + wave * 16 + quad * 4 + r;
        o[((size_t)b * Ss + qg) * INNERi + h * 64 + ni * 16 + col] =
            __float2bfloat16(accO[t][ni][r] * inv[r]);
      }
  }
}

// ---------------------------------------------------------------------------
// Epilogue gather: out[b,d,sp] = x[b, 255+sp, d]
// ---------------------------------------------------------------------------
__global__ void epilogue_kernel(const float* __restrict__ x, float* __restrict__ out)
{
  int idx = blockIdx.x * 256 + threadIdx.x;    // over B*D*256
  int sp = idx & 255;
  int bd = idx >> 8;
  int b = bd >> 9, d = bd & 511;
  out[idx] = x[((size_t)b * Ss + (NCc - 1) + sp) * Dd + d];
}

// ---------------------------------------------------------------------------
extern "C" void kernel_launch(void* const* d_in, const int* in_sizes, int n_in,
                              void* d_out, int out_size, void* d_ws, size_t ws_size,
                              hipStream_t stream)
{
  const float* z       = (const float*)d_in[0];
  const float* slots   = (const float*)d_in[1];
  const float* pos_emb = (const float*)d_in[2];
  const float* spos    = (const float*)d_in[3];
  const float* norm_w  = (const float*)d_in[4];
  const float* norm_b  = (const float*)d_in[5];
  const float* ln1_w   = (const float*)d_in[6];
  const float* ln1_b   = (const float*)d_in[7];
  const float* qkv_w   = (const float*)d_in[8];
  const float* out_w   = (const float*)d_in[9];
  const float* out_b   = (const float*)d_in[10];
  const float* ln2_w   = (const float*)d_in[11];
  const float* ln2_b   = (const float*)d_in[12];
  const float* mlp_w1  = (const float*)d_in[13];
  const float* mlp_b1  = (const float*)d_in[14];
  const float* mlp_w2  = (const float*)d_in[15];
  const float* mlp_b2  = (const float*)d_in[16];

  char* ws = (char*)d_ws;
  float*          xbuf = (float*)ws;
  __hip_bfloat16* ybuf = (__hip_bfloat16*)(ws + 33554432);
  __hip_bfloat16* qkvb = (__hip_bfloat16*)(ws + 50331648);
  __hip_bfloat16* obuf = (__hip_bfloat16*)(ws + 100663296);
  __hip_bfloat16* hbuf = (__hip_bfloat16*)(ws + 50331648);
  __hip_bfloat16* wT   = (__hip_bfloat16*)(ws + 117440512);

  const size_t WL = 3145728;

  dim3 tb(32, 8);
  transpose_w<<<dim3(1536 / 32, 512 / 32, 8), tb, 0, stream>>>(qkv_w,  wT + 0,       512, 1536, (size_t)512 * 1536, WL);
  transpose_w<<<dim3(512 / 32,  512 / 32, 8), tb, 0, stream>>>(out_w,  wT + 786432,  512, 512,  (size_t)512 * 512,  WL);
  transpose_w<<<dim3(2048 / 32, 512 / 32, 8), tb, 0, stream>>>(mlp_w1, wT + 1048576, 512, 2048, (size_t)512 * 2048, WL);
  transpose_w<<<dim3(512 / 32, 2048 / 32, 8), tb, 0, stream>>>(mlp_w2, wT + 2097152, 2048, 512, (size_t)2048 * 512, WL);

  prologue_kernel<<<Mrows, 64, 0, stream>>>(z, slots, pos_emb, spos, norm_w, norm_b, xbuf);

  for (int i = 0; i < 8; ++i) {
    const __hip_bfloat16* qkvT = wT + (size_t)i * WL;
    const __hip_bfloat16* outT = wT + (size_t)i * WL + 786432;
    const __hip_bfloat16* w1T  = wT + (size_t)i * WL + 1048576;
    const __hip_bfloat16* w2T  = wT + (size_t)i * WL + 2097152;

    ln_kernel<<<Mrows / 4, 256, 0, stream>>>(xbuf, ln1_w + i * Dd, ln1_b + i * Dd, ybuf);
    gemm_bt<0><<<dim3((1536 / 128) * (Mrows / 128)), 256, 0, stream>>>(
        ybuf, qkvT, nullptr, nullptr, qkvb, Mrows, 1536, 512);
    attn_pair<<<dim3(4, NHh, Bb), 256, 0, stream>>>(qkvb, obuf);
    gemm_bt<1><<<dim3((512 / 128) * (Mrows / 128)), 256, 0, stream>>>(
        obuf, outT, out_b + i * Dd, xbuf, xbuf, Mrows, 512, 512);
    ln_kernel<<<Mrows / 4, 256, 0, stream>>>(xbuf, ln2_w + i * Dd, ln2_b + i * Dd, ybuf);
    gemm_bt<2><<<dim3((2048 / 128) * (Mrows / 128)), 256, 0, stream>>>(
        ybuf, w1T, mlp_b1 + i * MLPm, nullptr, hbuf, Mrows, 2048, 512);
    gemm_bt<1><<<dim3((512 / 128) * (Mrows / 128)), 256, 0, stream>>>(
        hbuf, w2T, mlp_b2 + i * Dd, xbuf, xbuf, Mrows, 512, 2048);
  }

  epilogue_kernel<<<(Bb * Dd * 256) / 256, 256, 0, stream>>>(xbuf, (float*)d_out);
}